// Round 1
// baseline (83.314 us; speedup 1.0000x reference)
//
#include <hip/hip_runtime.h>
#include <stdint.h>

static constexpr int B_N   = 16;
static constexpr int P_N   = 16384;
static constexpr int D_Z   = 512;
static constexpr int D_PHI = 256;
static constexpr int D_R   = 64;
static constexpr int H     = 96;    // H1 == H2
static constexpr int KP    = 832;   // 3*D_PHI + D_R (pair-feature dim)

using f32x4 = __attribute__((ext_vector_type(4))) float;
using s16x8 = __attribute__((ext_vector_type(8))) short;

__device__ __forceinline__ unsigned short f2bf(float f) {
    union { float f; uint32_t u; } v; v.f = f;
    return (unsigned short)((v.u + 0x7FFFu + ((v.u >> 16) & 1u)) >> 16);
}

// tanh-form GELU == x * sigmoid(1.5957691*(x + 0.044715 x^3)); max abs err vs exact ~3e-4
__device__ __forceinline__ float gelu_f(float x) {
    float x3 = x * x * x;
    float z = 1.5957691216057308f * (x + 0.044715f * x3);
    return x / (1.0f + __expf(-z));
}

// ---------------------------------------------------------------------------
// prep: blocks 0..15  : gq_pre[b][n] = sum_k g_q[b][k]*W1[k][n] + b1[n]  (f32)
//       blocks 16..327: W1pT[n][k] = bf16(W1[512+k][n])   (96 x 832)
//       blocks 328..363: W2T[n][k] = bf16(W2[k][n])       (96 x 96)
// ---------------------------------------------------------------------------
__global__ __launch_bounds__(256) void prep_kernel(
    const float* __restrict__ g_q, const float* __restrict__ W1,
    const float* __restrict__ b1, const float* __restrict__ W2,
    float* __restrict__ gq_pre, unsigned short* __restrict__ W1pT,
    unsigned short* __restrict__ W2T)
{
    __shared__ float gql[D_Z];
    __shared__ float red[192];
    const int blk = blockIdx.x;
    const int t = threadIdx.x;
    if (blk < 16) {
        const int b = blk;
        for (int i = t; i < D_Z; i += 256) gql[i] = g_q[b * D_Z + i];
        __syncthreads();
        float acc = 0.f;
        if (t < 192) {
            const int n = t % 96, s = t / 96;
            const int k0 = s * 256;
            #pragma unroll 8
            for (int k = 0; k < 256; ++k)
                acc += gql[k0 + k] * W1[(k0 + k) * H + n];
            red[t] = acc;
        }
        __syncthreads();
        if (t < 96) gq_pre[b * H + t] = red[t] + red[t + 96] + b1[t];
    } else if (blk < 328) {
        const int e = (blk - 16) * 256 + t;           // < 96*832 = 79872
        const int n = e / KP, k = e % KP;
        W1pT[e] = f2bf(W1[(D_Z + k) * H + n]);
    } else {
        const int e = (blk - 328) * 256 + t;          // < 96*96 = 9216
        const int n = e / H, k = e % H;
        W2T[e] = f2bf(W2[k * H + n]);
    }
}

// ---------------------------------------------------------------------------
// P1: pair_pre[p][n] = pair_feats[p] @ W1p   (M=16384, K=832, N=96) bf16 MFMA
//     64 pairs per block, 4 waves, wave w handles rows w*16..w*16+15
// ---------------------------------------------------------------------------
__global__ __launch_bounds__(256) void pair_pre_kernel(
    const float* __restrict__ Phi, const int* __restrict__ pidx,
    const float* __restrict__ rel, const unsigned short* __restrict__ W1pT,
    float* __restrict__ pair_pre)
{
    __shared__ int idx_i[64], idx_j[64];
    __shared__ __align__(16) unsigned short feats[64 * 40]; // stride 40 bf16 (80B)
    __shared__ __align__(16) unsigned short Bt[96 * 40];
    const int t = threadIdx.x;
    const int p0 = blockIdx.x * 64;
    if (t < 64) {
        idx_i[t] = pidx[2 * (p0 + t)];
        idx_j[t] = pidx[2 * (p0 + t) + 1];
    }
    __syncthreads();

    f32x4 acc[6];
    #pragma unroll
    for (int nf = 0; nf < 6; ++nf) acc[nf] = (f32x4){0.f, 0.f, 0.f, 0.f};

    const int row = t & 63;   // pair within tile
    const int hi  = t >> 6;   // wave id == k-subslice (8 elems)
    const int l   = t & 63;
    const int lr  = l & 15, l4 = l >> 4;

    for (int kc = 0; kc < 26; ++kc) {
        const int k0 = kc * 32;
        const int kk = k0 + hi * 8;          // wave-uniform
        float f[8];
        if (kk < 768) {
            const int kb = kk & 255;
            const float* PI = Phi + idx_i[row] * D_PHI + kb;
            const float* PJ = Phi + idx_j[row] * D_PHI + kb;
            float4 a0 = *(const float4*)PI,  a1 = *(const float4*)(PI + 4);
            float4 c0 = *(const float4*)PJ,  c1 = *(const float4*)(PJ + 4);
            if (kk < 256) {
                f[0]=a0.x+c0.x; f[1]=a0.y+c0.y; f[2]=a0.z+c0.z; f[3]=a0.w+c0.w;
                f[4]=a1.x+c1.x; f[5]=a1.y+c1.y; f[6]=a1.z+c1.z; f[7]=a1.w+c1.w;
            } else if (kk < 512) {
                f[0]=fabsf(a0.x-c0.x); f[1]=fabsf(a0.y-c0.y); f[2]=fabsf(a0.z-c0.z); f[3]=fabsf(a0.w-c0.w);
                f[4]=fabsf(a1.x-c1.x); f[5]=fabsf(a1.y-c1.y); f[6]=fabsf(a1.z-c1.z); f[7]=fabsf(a1.w-c1.w);
            } else {
                f[0]=a0.x*c0.x; f[1]=a0.y*c0.y; f[2]=a0.z*c0.z; f[3]=a0.w*c0.w;
                f[4]=a1.x*c1.x; f[5]=a1.y*c1.y; f[6]=a1.z*c1.z; f[7]=a1.w*c1.w;
            }
        } else {
            const float* R = rel + (p0 + row) * D_R + (kk - 768);
            float4 a0 = *(const float4*)R, a1 = *(const float4*)(R + 4);
            f[0]=a0.x; f[1]=a0.y; f[2]=a0.z; f[3]=a0.w;
            f[4]=a1.x; f[5]=a1.y; f[6]=a1.z; f[7]=a1.w;
        }
        uint4 pk;
        pk.x = f2bf(f[0]) | ((uint32_t)f2bf(f[1]) << 16);
        pk.y = f2bf(f[2]) | ((uint32_t)f2bf(f[3]) << 16);
        pk.z = f2bf(f[4]) | ((uint32_t)f2bf(f[5]) << 16);
        pk.w = f2bf(f[6]) | ((uint32_t)f2bf(f[7]) << 16);
        *(uint4*)&feats[row * 40 + hi * 8] = pk;

        if (t < 192) {   // stage B chunk: W1pT[n][k0..k0+31]
            const int n = t >> 1, hf = t & 1;
            const uint4* src = (const uint4*)(W1pT + n * KP + k0 + hf * 16);
            uint4 v0 = src[0], v1 = src[1];
            uint4* dst = (uint4*)&Bt[n * 40 + hf * 16];
            dst[0] = v0; dst[1] = v1;
        }
        __syncthreads();

        const s16x8 a = *(const s16x8*)&feats[(hi * 16 + lr) * 40 + l4 * 8];
        #pragma unroll
        for (int nf = 0; nf < 6; ++nf) {
            const s16x8 bb = *(const s16x8*)&Bt[(nf * 16 + lr) * 40 + l4 * 8];
            acc[nf] = __builtin_amdgcn_mfma_f32_16x16x32_bf16(a, bb, acc[nf], 0, 0, 0);
        }
        __syncthreads();
    }

    #pragma unroll
    for (int nf = 0; nf < 6; ++nf)
        #pragma unroll
        for (int r = 0; r < 4; ++r) {
            const int prow = p0 + hi * 16 + l4 * 4 + r;   // hi == wave id
            const int col  = nf * 16 + lr;
            pair_pre[prow * H + col] = acc[nf][r];
        }
}

// ---------------------------------------------------------------------------
// F: fused gelu(y1) -> @W2T -> gelu -> dot W3.  8 pairs x 16 b = 128 rows/block
// ---------------------------------------------------------------------------
__global__ __launch_bounds__(256) void fused_kernel(
    const float* __restrict__ gq_pre, const float* __restrict__ pair_pre,
    const unsigned short* __restrict__ W2T_g, const float* __restrict__ b2,
    const float* __restrict__ W3, const float* __restrict__ b3,
    float* __restrict__ out)
{
    __shared__ __align__(16) unsigned short h1[128 * 104];  // stride 104 bf16 (208B)
    __shared__ __align__(16) unsigned short w2t[96 * 104];
    __shared__ float b2l[96], w3l[96];
    const int t = threadIdx.x;
    const int p0 = blockIdx.x * 8;

    if (t < 192) {   // stage W2T (96B per half-row = 6 uint4)
        const int n = t >> 1, hf = t & 1;
        const uint4* src = (const uint4*)(W2T_g + n * 96 + hf * 48);
        uint4* dst = (uint4*)&w2t[n * 104 + hf * 48];
        #pragma unroll
        for (int i = 0; i < 6; ++i) dst[i] = src[i];
    }
    if (t < 96) { b2l[t] = b2[t]; w3l[t] = W3[t]; }

    {   // phase B: h1[r][n] = bf16(gelu(gq_pre[b][n] + pair_pre[p0+pl][n]))
        const int r = t >> 1, half = t & 1;
        const int b = r & 15, pl = r >> 4;
        const float* gr = gq_pre + b * H + half * 48;
        const float* pr = pair_pre + (p0 + pl) * H + half * 48;
        unsigned short* dst = &h1[r * 104 + half * 48];
        #pragma unroll
        for (int c = 0; c < 12; ++c) {
            float4 g = *(const float4*)(gr + c * 4);
            float4 q = *(const float4*)(pr + c * 4);
            float y0 = gelu_f(g.x + q.x);
            float y1v = gelu_f(g.y + q.y);
            float y2v = gelu_f(g.z + q.z);
            float y3v = gelu_f(g.w + q.w);
            uint2 pk;
            pk.x = f2bf(y0)  | ((uint32_t)f2bf(y1v) << 16);
            pk.y = f2bf(y2v) | ((uint32_t)f2bf(y3v) << 16);
            *(uint2*)(dst + c * 4) = pk;
        }
    }
    __syncthreads();

    // phase C: layer-2 MFMA.  wave w owns rows m0..m0+31 (2 m-frags)
    const int w = t >> 6, l = t & 63;
    const int m0 = w * 32;
    const int lr = l & 15, hi4 = l >> 4;
    f32x4 acc[2][6];
    #pragma unroll
    for (int mf = 0; mf < 2; ++mf)
        #pragma unroll
        for (int nf = 0; nf < 6; ++nf) {
            const float bv = b2l[nf * 16 + lr];
            acc[mf][nf] = (f32x4){bv, bv, bv, bv};
        }
    #pragma unroll
    for (int ks = 0; ks < 3; ++ks) {
        const s16x8 a0 = *(const s16x8*)&h1[(m0 + lr) * 104 + ks * 32 + hi4 * 8];
        const s16x8 a1 = *(const s16x8*)&h1[(m0 + 16 + lr) * 104 + ks * 32 + hi4 * 8];
        #pragma unroll
        for (int nf = 0; nf < 6; ++nf) {
            const s16x8 bb = *(const s16x8*)&w2t[(nf * 16 + lr) * 104 + ks * 32 + hi4 * 8];
            acc[0][nf] = __builtin_amdgcn_mfma_f32_16x16x32_bf16(a0, bb, acc[0][nf], 0, 0, 0);
            acc[1][nf] = __builtin_amdgcn_mfma_f32_16x16x32_bf16(a1, bb, acc[1][nf], 0, 0, 0);
        }
    }

    // phase D: gelu(y2) dot W3, reduce over the 16 col-lanes, write out
    float part[2][4] = {{0.f,0.f,0.f,0.f},{0.f,0.f,0.f,0.f}};
    #pragma unroll
    for (int mf = 0; mf < 2; ++mf)
        #pragma unroll
        for (int nf = 0; nf < 6; ++nf) {
            const float wv = w3l[nf * 16 + lr];
            #pragma unroll
            for (int r4 = 0; r4 < 4; ++r4)
                part[mf][r4] += gelu_f(acc[mf][nf][r4]) * wv;
        }
    #pragma unroll
    for (int mask = 1; mask <= 8; mask <<= 1)
        #pragma unroll
        for (int mf = 0; mf < 2; ++mf)
            #pragma unroll
            for (int r4 = 0; r4 < 4; ++r4)
                part[mf][r4] += __shfl_xor(part[mf][r4], mask, 64);
    if (lr == 0) {
        const float b3v = b3[0];
        #pragma unroll
        for (int mf = 0; mf < 2; ++mf)
            #pragma unroll
            for (int r4 = 0; r4 < 4; ++r4) {
                const int row = m0 + 16 * mf + 4 * hi4 + r4;
                const int b = row & 15, pl = row >> 4;
                out[b * P_N + p0 + pl] = part[mf][r4] + b3v;
            }
    }
}

extern "C" void kernel_launch(void* const* d_in, const int* in_sizes, int n_in,
                              void* d_out, int out_size, void* d_ws, size_t ws_size,
                              hipStream_t stream)
{
    const float* g_q  = (const float*)d_in[0];
    const float* Phi  = (const float*)d_in[1];
    const int*   pidx = (const int*)d_in[2];
    const float* rel  = (const float*)d_in[3];
    const float* W1   = (const float*)d_in[4];
    const float* b1   = (const float*)d_in[5];
    const float* W2   = (const float*)d_in[6];
    const float* b2   = (const float*)d_in[7];
    const float* W3   = (const float*)d_in[8];
    const float* b3   = (const float*)d_in[9];
    float* out = (float*)d_out;

    char* ws = (char*)d_ws;
    float*          gq_pre   = (float*)(ws + 0);                 // 16*96*4   = 6144
    unsigned short* W1pT     = (unsigned short*)(ws + 8192);     // 96*832*2  = 159744
    unsigned short* W2T      = (unsigned short*)(ws + 167936);   // 96*96*2   = 18432
    float*          pair_pre = (float*)(ws + 196608);            // 16384*96*4 = 6291456

    hipLaunchKernelGGL(prep_kernel, dim3(364), dim3(256), 0, stream,
                       g_q, W1, b1, W2, gq_pre, W1pT, W2T);
    hipLaunchKernelGGL(pair_pre_kernel, dim3(256), dim3(256), 0, stream,
                       Phi, pidx, rel, W1pT, pair_pre);
    hipLaunchKernelGGL(fused_kernel, dim3(2048), dim3(256), 0, stream,
                       gq_pre, pair_pre, W2T, b2, W3, b3, out);
}

// Round 2
// 57.969 us; speedup vs baseline: 1.4372x; 1.4372x over previous
//
#include <hip/hip_runtime.h>
#include <stdint.h>

static constexpr int P_N   = 16384;
static constexpr int D_Z   = 512;
static constexpr int D_PHI = 256;
static constexpr int D_R   = 64;
static constexpr int H     = 96;    // H1 == H2
static constexpr int KP    = 832;   // 3*D_PHI + D_R

using f32x4 = __attribute__((ext_vector_type(4))) float;
using s16x8 = __attribute__((ext_vector_type(8))) short;

__device__ __forceinline__ unsigned short f2bf(float f) {
    union { float f; uint32_t u; } v; v.f = f;
    return (unsigned short)((v.u + 0x7FFFu + ((v.u >> 16) & 1u)) >> 16);
}

// gelu(x) ~= x * sigmoid(1.5957691*(x + 0.044715 x^3))
//         =  x * rcp(1 + exp2(x*(-2.3022126 - 0.1029444 x^2)))
__device__ __forceinline__ float gelu_f(float x) {
    float x2 = x * x;
    float u  = __builtin_fmaf(-0.1029444f, x2, -2.3022126f);
    float e  = __builtin_amdgcn_exp2f(x * u);
    return x * __builtin_amdgcn_rcpf(1.0f + e);
}

// ---------------------------------------------------------------------------
// prep: blocks 0..15  : gq_pre[b][n] = g_q[b] @ W1[:512] + b1   (f32)
//       blocks 16..327: W1pT[n][k] = bf16(W1[512+k][n])   (96 x 832)
//       blocks 328..363: W2T[n][k] = bf16(W2[k][n])       (96 x 96)
// ---------------------------------------------------------------------------
__global__ __launch_bounds__(256) void prep_kernel(
    const float* __restrict__ g_q, const float* __restrict__ W1,
    const float* __restrict__ b1, const float* __restrict__ W2,
    float* __restrict__ gq_pre, unsigned short* __restrict__ W1pT,
    unsigned short* __restrict__ W2T)
{
    __shared__ float gql[D_Z];
    __shared__ float red[192];
    const int blk = blockIdx.x;
    const int t = threadIdx.x;
    if (blk < 16) {
        const int b = blk;
        for (int i = t; i < D_Z; i += 256) gql[i] = g_q[b * D_Z + i];
        __syncthreads();
        float acc = 0.f;
        if (t < 192) {
            const int n = t % 96, s = t / 96;
            const int k0 = s * 256;
            #pragma unroll 8
            for (int k = 0; k < 256; ++k)
                acc += gql[k0 + k] * W1[(k0 + k) * H + n];
            red[t] = acc;
        }
        __syncthreads();
        if (t < 96) gq_pre[b * H + t] = red[t] + red[t + 96] + b1[t];
    } else if (blk < 328) {
        const int e = (blk - 16) * 256 + t;           // < 96*832
        const int n = e / KP, k = e % KP;
        W1pT[e] = f2bf(W1[(D_Z + k) * H + n]);
    } else {
        const int e = (blk - 328) * 256 + t;          // < 96*96
        const int n = e / H, k = e % H;
        W2T[e] = f2bf(W2[k * H + n]);
    }
}

// ---------------------------------------------------------------------------
// fused2: 16 pairs x all 16 b = 256 output rows per block. 512 thr (8 waves).
//   phase 0: build pair feats (16 x 832 bf16) in LDS, stride 840
//   phase 1: waves 0..5: y1p[16][96] = feats @ W1p  (wave w -> cols w*16..+16)
//   phase 2: all 8 waves: A-frags = bf16(gelu(gq_pre[b] + y1p[pl])) in regs,
//            layer-2 MFMA vs W2T (global, L1-resident), acc init = b2
//   phase 3: gelu -> dot W3 -> shfl-reduce over 16 col-lanes -> out[b][p]
// row mapping: global row = pl*16 + b; wave w owns rows w*32..w*32+31
//   A-frag row lr -> b = lr, pl = 2w+mf.  D row (l4*4+r4) -> b, p = p0+2w+mf
// ---------------------------------------------------------------------------
__global__ __launch_bounds__(512, 4) void fused2_kernel(
    const float* __restrict__ Phi, const int* __restrict__ pidx,
    const float* __restrict__ rel, const unsigned short* __restrict__ W1pT,
    const float* __restrict__ gq_pre, const unsigned short* __restrict__ W2T,
    const float* __restrict__ b2, const float* __restrict__ W3,
    const float* __restrict__ b3, float* __restrict__ out)
{
    __shared__ int li[16], lj[16];
    __shared__ __align__(16) unsigned short feats[16 * 840]; // stride 840 bf16
    __shared__ __align__(16) float y1s[16 * 96];
    const int t = threadIdx.x;
    const int p0 = blockIdx.x * 16;

    if (t < 16) { li[t] = pidx[2 * (p0 + t)]; lj[t] = pidx[2 * (p0 + t) + 1]; }
    __syncthreads();

    // phase 0: 1664 tasks of 8 feature elems each
    for (int task = t; task < 1664; task += 512) {
        const int pair = task / 104;
        const int k = (task - pair * 104) * 8;
        float f[8];
        if (k < 768) {
            const int kb = k & 255;
            const float* PI = Phi + li[pair] * D_PHI + kb;
            const float* PJ = Phi + lj[pair] * D_PHI + kb;
            float4 a0 = *(const float4*)PI, a1 = *(const float4*)(PI + 4);
            float4 c0 = *(const float4*)PJ, c1 = *(const float4*)(PJ + 4);
            if (k < 256) {
                f[0]=a0.x+c0.x; f[1]=a0.y+c0.y; f[2]=a0.z+c0.z; f[3]=a0.w+c0.w;
                f[4]=a1.x+c1.x; f[5]=a1.y+c1.y; f[6]=a1.z+c1.z; f[7]=a1.w+c1.w;
            } else if (k < 512) {
                f[0]=fabsf(a0.x-c0.x); f[1]=fabsf(a0.y-c0.y); f[2]=fabsf(a0.z-c0.z); f[3]=fabsf(a0.w-c0.w);
                f[4]=fabsf(a1.x-c1.x); f[5]=fabsf(a1.y-c1.y); f[6]=fabsf(a1.z-c1.z); f[7]=fabsf(a1.w-c1.w);
            } else {
                f[0]=a0.x*c0.x; f[1]=a0.y*c0.y; f[2]=a0.z*c0.z; f[3]=a0.w*c0.w;
                f[4]=a1.x*c1.x; f[5]=a1.y*c1.y; f[6]=a1.z*c1.z; f[7]=a1.w*c1.w;
            }
        } else {
            const float* R = rel + (p0 + pair) * D_R + (k - 768);
            float4 a0 = *(const float4*)R, a1 = *(const float4*)(R + 4);
            f[0]=a0.x; f[1]=a0.y; f[2]=a0.z; f[3]=a0.w;
            f[4]=a1.x; f[5]=a1.y; f[6]=a1.z; f[7]=a1.w;
        }
        uint4 pk;
        pk.x = f2bf(f[0]) | ((uint32_t)f2bf(f[1]) << 16);
        pk.y = f2bf(f[2]) | ((uint32_t)f2bf(f[3]) << 16);
        pk.z = f2bf(f[4]) | ((uint32_t)f2bf(f[5]) << 16);
        pk.w = f2bf(f[6]) | ((uint32_t)f2bf(f[7]) << 16);
        *(uint4*)&feats[pair * 840 + k] = pk;
    }
    __syncthreads();

    const int w  = t >> 6;
    const int l  = t & 63;
    const int lr = l & 15, l4 = l >> 4;

    // phase 1: pair-part of layer 1 (waves 0..5, wave w -> col block w)
    if (w < 6) {
        f32x4 acc = (f32x4){0.f, 0.f, 0.f, 0.f};
        const unsigned short* Brow = W1pT + (w * 16 + lr) * KP + l4 * 8;
        const unsigned short* Arow = &feats[lr * 840 + l4 * 8];
        #pragma unroll 2
        for (int kc = 0; kc < 26; ++kc) {
            const s16x8 a  = *(const s16x8*)(Arow + kc * 32);
            const s16x8 bb = *(const s16x8*)(Brow + kc * 32);
            acc = __builtin_amdgcn_mfma_f32_16x16x32_bf16(a, bb, acc, 0, 0, 0);
        }
        #pragma unroll
        for (int r = 0; r < 4; ++r)
            y1s[(l4 * 4 + r) * 96 + w * 16 + lr] = acc[r];
    }
    __syncthreads();

    // phase 2a: layer-2 A-fragments directly in registers (consumer layout)
    s16x8 afr[2][3];
    #pragma unroll
    for (int ks = 0; ks < 3; ++ks) {
        const int c = ks * 32 + l4 * 8;
        const float* gp = gq_pre + lr * 96 + c;
        float4 g0 = *(const float4*)gp, g1 = *(const float4*)(gp + 4);
        #pragma unroll
        for (int mf = 0; mf < 2; ++mf) {
            const float* yp = &y1s[(2 * w + mf) * 96 + c];   // broadcast read
            float4 y0 = *(const float4*)yp, y1v = *(const float4*)(yp + 4);
            union { s16x8 v; unsigned short u[8]; } pk;
            pk.u[0] = f2bf(gelu_f(g0.x + y0.x));
            pk.u[1] = f2bf(gelu_f(g0.y + y0.y));
            pk.u[2] = f2bf(gelu_f(g0.z + y0.z));
            pk.u[3] = f2bf(gelu_f(g0.w + y0.w));
            pk.u[4] = f2bf(gelu_f(g1.x + y1v.x));
            pk.u[5] = f2bf(gelu_f(g1.y + y1v.y));
            pk.u[6] = f2bf(gelu_f(g1.z + y1v.z));
            pk.u[7] = f2bf(gelu_f(g1.w + y1v.w));
            afr[mf][ks] = pk.v;
        }
    }

    // phase 2b: layer-2 MFMA, B from global (L1-resident W2T)
    f32x4 acc2[2][6];
    #pragma unroll
    for (int nf = 0; nf < 6; ++nf) {
        const float bv = b2[nf * 16 + lr];
        acc2[0][nf] = (f32x4){bv, bv, bv, bv};
        acc2[1][nf] = (f32x4){bv, bv, bv, bv};
    }
    #pragma unroll
    for (int ks = 0; ks < 3; ++ks) {
        #pragma unroll
        for (int nf = 0; nf < 6; ++nf) {
            const s16x8 bb = *(const s16x8*)(W2T + (nf * 16 + lr) * H + ks * 32 + l4 * 8);
            acc2[0][nf] = __builtin_amdgcn_mfma_f32_16x16x32_bf16(afr[0][ks], bb, acc2[0][nf], 0, 0, 0);
            acc2[1][nf] = __builtin_amdgcn_mfma_f32_16x16x32_bf16(afr[1][ks], bb, acc2[1][nf], 0, 0, 0);
        }
    }

    // phase 3: gelu -> dot W3 -> reduce over 16 col-lanes -> store
    float part[2][4] = {{0.f,0.f,0.f,0.f},{0.f,0.f,0.f,0.f}};
    #pragma unroll
    for (int nf = 0; nf < 6; ++nf) {
        const float wv = W3[nf * 16 + lr];
        #pragma unroll
        for (int mf = 0; mf < 2; ++mf)
            #pragma unroll
            for (int r4 = 0; r4 < 4; ++r4)
                part[mf][r4] = __builtin_fmaf(gelu_f(acc2[mf][nf][r4]), wv, part[mf][r4]);
    }
    #pragma unroll
    for (int mask = 1; mask <= 8; mask <<= 1)
        #pragma unroll
        for (int mf = 0; mf < 2; ++mf)
            #pragma unroll
            for (int r4 = 0; r4 < 4; ++r4)
                part[mf][r4] += __shfl_xor(part[mf][r4], mask, 64);
    if (lr == 0) {
        const float b3v = b3[0];
        #pragma unroll
        for (int mf = 0; mf < 2; ++mf)
            #pragma unroll
            for (int r4 = 0; r4 < 4; ++r4)
                out[(l4 * 4 + r4) * P_N + p0 + 2 * w + mf] = part[mf][r4] + b3v;
    }
}

extern "C" void kernel_launch(void* const* d_in, const int* in_sizes, int n_in,
                              void* d_out, int out_size, void* d_ws, size_t ws_size,
                              hipStream_t stream)
{
    const float* g_q  = (const float*)d_in[0];
    const float* Phi  = (const float*)d_in[1];
    const int*   pidx = (const int*)d_in[2];
    const float* rel  = (const float*)d_in[3];
    const float* W1   = (const float*)d_in[4];
    const float* b1   = (const float*)d_in[5];
    const float* W2   = (const float*)d_in[6];
    const float* b2   = (const float*)d_in[7];
    const float* W3   = (const float*)d_in[8];
    const float* b3   = (const float*)d_in[9];
    float* out = (float*)d_out;

    char* ws = (char*)d_ws;
    float*          gq_pre = (float*)(ws + 0);               // 16*96*4
    unsigned short* W1pT   = (unsigned short*)(ws + 8192);   // 96*832*2
    unsigned short* W2T    = (unsigned short*)(ws + 167936); // 96*96*2

    hipLaunchKernelGGL(prep_kernel, dim3(364), dim3(256), 0, stream,
                       g_q, W1, b1, W2, gq_pre, W1pT, W2T);
    hipLaunchKernelGGL(fused2_kernel, dim3(P_N / 16), dim3(512), 0, stream,
                       Phi, pidx, rel, W1pT, gq_pre, W2T, b2, W3, b3, out);
}